// Round 16
// baseline (2115.482 us; speedup 1.0000x reference)
//
#include <hip/hip_runtime.h>
#include <math.h>
#include <float.h>

#define DIM 256
// Tie policy (verified PASS R6-R15 pre-timing — do not change):
#define EPS_TIE 1e-4
#define PREFER_LOWER 1
// Flag margins (verified absmax 0 in R13/R14/R15 — do not change):
#define MARGIN_MERGE 0.75f
#define MARGIN_HALF  0.30f
#define MARGIN_FALLBACK 0.125f

typedef __attribute__((ext_vector_type(8))) short short8;   // 8 bf16 = 4 VGPR
typedef __attribute__((ext_vector_type(4))) float f32x4;

__device__ __forceinline__ unsigned short f32_to_bf16_rne(float f) {
    unsigned int u = __float_as_uint(f);
    u += 0x7fffu + ((u >> 16) & 1u);
    return (unsigned short)(u >> 16);
}
__device__ __forceinline__ void nt_store4(float* p, f32x4 v) {
    __builtin_nontemporal_store(v, (f32x4*)p);
}

// |e_j|^2: f32 (fast pass) + fp64 (refine). No other state.
__global__ void esq_kernel(const float* __restrict__ embed, float* __restrict__ esq,
                           double* __restrict__ esqd) {
    const int j = blockIdx.x;
    const int lane = threadIdx.x;  // 64
    float4 v = *reinterpret_cast<const float4*>(embed + (size_t)j * DIM + lane * 4);
    float s = v.x * v.x + v.y * v.y + v.z * v.z + v.w * v.w;
    double sd = (double)v.x * v.x + (double)v.y * v.y
              + (double)v.z * v.z + (double)v.w * v.w;
#pragma unroll
    for (int m = 32; m >= 1; m >>= 1) {
        s  += __shfl_xor(s, m, 64);
        sd += __shfl_xor(sd, m, 64);
    }
    if (lane == 0) { esq[j] = s; esqd[j] = sd; }
}

// embed -> fragment-major bf16 (B operand). UNCHANGED (verified).
__global__ void efrag_kernel(const float* __restrict__ embed,
                             unsigned short* __restrict__ ehi) {
    const int b = blockIdx.x;          // 0..511
    const int l = threadIdx.x;         // 0..63
    const int ct = b >> 3, s = b & 7;
    const int col = ct * 16 + (l & 15);
    const int kb  = s * 32 + (l >> 4) * 8;
    const float* src = embed + (size_t)col * DIM + kb;
    float4 v0 = *reinterpret_cast<const float4*>(src);
    float4 v1 = *reinterpret_cast<const float4*>(src + 4);
    float vv[8] = {v0.x, v0.y, v0.z, v0.w, v1.x, v1.y, v1.z, v1.w};
    size_t base = ((size_t)b * 64 + l) * 8;
#pragma unroll
    for (int i = 0; i < 8; ++i) ehi[base + i] = f32_to_bf16_rne(vv[i]);
}

// ---- fast pass (VERIFIED R13/R14/R15) ----
__global__ __launch_bounds__(512, 2) void
vq_fast_kernel(const float* __restrict__ x, const unsigned short* __restrict__ ehi,
               const float* __restrict__ esq, float* __restrict__ pv1,
               float* __restrict__ pv2, int* __restrict__ pi1, int N) {
    __shared__ unsigned short xfrag[4][8][512];   // 32 KB
    __shared__ float wv1[8][64], wv2[8][64];
    __shared__ int   wi1[8][64];
    __shared__ float esq_l[512];

    const int t  = threadIdx.x;
    const int w  = t >> 6;
    const int l  = t & 63;
    const int ar = l & 15;
    const int ag = l >> 4;
    const int half  = blockIdx.x & 1;
    const int rbase = (blockIdx.x >> 1) * 512;
    const int cbase = half * 512;

    for (int i = t; i < 512; i += 512) esq_l[i] = esq[cbase + i];

    short8 eh[4][8];
#pragma unroll
    for (int ct = 0; ct < 4; ++ct)
#pragma unroll
        for (int s = 0; s < 8; ++s) {
            const int ctg = half * 32 + w * 4 + ct;
            eh[ct][s] = *reinterpret_cast<const short8*>(
                ehi + (((size_t)ctg * 8 + s) * 64 + l) * 8);
        }

    for (int tile = 0; tile < 8; ++tile) {
        const int trow0 = rbase + tile * 64;
        __syncthreads();
#pragma unroll
        for (int i = 0; i < 4; ++i) {
            const int f = w * 4 + i, rt = f >> 3, s = f & 7;
            const float* src = x + (size_t)(trow0 + rt * 16 + ar) * DIM + s * 32 + ag * 8;
            float4 v0 = *reinterpret_cast<const float4*>(src);
            float4 v1 = *reinterpret_cast<const float4*>(src + 4);
            float vv[8] = {v0.x, v0.y, v0.z, v0.w, v1.x, v1.y, v1.z, v1.w};
            short8 hv;
#pragma unroll
            for (int j = 0; j < 8; ++j) hv[j] = (short)f32_to_bf16_rne(vv[j]);
            *reinterpret_cast<short8*>(&xfrag[rt][s][l * 8]) = hv;
        }
        __syncthreads();

        f32x4 acc[4][4];
#pragma unroll
        for (int rt = 0; rt < 4; ++rt)
#pragma unroll
            for (int ct = 0; ct < 4; ++ct) acc[rt][ct] = (f32x4)0.0f;

#pragma unroll
        for (int s = 0; s < 8; ++s)
#pragma unroll
            for (int rt = 0; rt < 4; ++rt) {
                short8 xa = *reinterpret_cast<const short8*>(&xfrag[rt][s][l * 8]);
#pragma unroll
                for (int ct = 0; ct < 4; ++ct)
                    acc[rt][ct] = __builtin_amdgcn_mfma_f32_16x16x32_bf16(
                        xa, eh[ct][s], acc[rt][ct], 0, 0, 0);
            }

#pragma unroll
        for (int rt = 0; rt < 4; ++rt)
#pragma unroll
            for (int r = 0; r < 4; ++r) {
                float v1 = INFINITY, v2 = INFINITY; int i1 = 0;
#pragma unroll
                for (int ct = 0; ct < 4; ++ct) {
                    const int col = cbase + w * 64 + ct * 16 + ar;
                    float sc = fmaf(-2.0f, acc[rt][ct][r], esq_l[w * 64 + ct * 16 + ar]);
                    if (sc < v1) { v2 = v1; v1 = sc; i1 = col; }
                    else if (sc < v2) v2 = sc;
                }
#pragma unroll
                for (int m = 1; m < 16; m <<= 1) {
                    float ov1 = __shfl_xor(v1, m, 64);
                    int   oi1 = __shfl_xor(i1, m, 64);
                    float ov2 = __shfl_xor(v2, m, 64);
                    float nv2 = fminf(fmaxf(v1, ov1), fminf(v2, ov2));
                    if (ov1 < v1 || (ov1 == v1 && oi1 < i1)) { v1 = ov1; i1 = oi1; }
                    v2 = nv2;
                }
                if (ar == 0) {
                    const int rl = rt * 16 + ag * 4 + r;
                    wv1[w][rl] = v1; wi1[w][rl] = i1; wv2[w][rl] = v2;
                }
            }
        __syncthreads();
        if (t < 64) {
            float v1 = wv1[0][t]; int i1 = wi1[0][t]; float v2 = wv2[0][t];
#pragma unroll
            for (int ww = 1; ww < 8; ++ww) {
                float ov1 = wv1[ww][t]; int oi1 = wi1[ww][t]; float ov2 = wv2[ww][t];
                float nv2 = fminf(fmaxf(v1, ov1), fminf(v2, ov2));
                if (ov1 < v1 || (ov1 == v1 && oi1 < i1)) { v1 = ov1; i1 = oi1; }
                v2 = nv2;
            }
            const size_t pidx = (size_t)(trow0 + t) * 2 + half;
            pv1[pidx] = v1; pv2[pidx] = v2; pi1[pidx] = i1;
        }
    }
}

// ---- merge halves + outputs + in-block coalesced fp64 refine + tie policy ----
// Block-local LDS flag list (R13/R14-proven pattern: no cross-kernel state).
// Refine body: wave w scans j in [w*256, w*256+256) with coalesced float4 reads
// + 6-step fp64 butterfly (R15's fast body).
__global__ __launch_bounds__(256) void
vq_merge_refine_kernel(const float* __restrict__ x, const float* __restrict__ embed,
                       const float* __restrict__ pv1, const float* __restrict__ pv2,
                       const int* __restrict__ pi1, const double* __restrict__ esqd,
                       float* __restrict__ out, int N) {
    __shared__ int    rowidx[64];
    __shared__ int    flr[64];
    __shared__ int    nflag;
    __shared__ double sv1[4], sv2[4];
    __shared__ int    si1[4], si2[4];
    __shared__ int    sidx;

    const int t = threadIdx.x;
    const int w = t >> 6, l = t & 63;
    const int row0 = blockIdx.x * 64;
    if (t == 0) nflag = 0;
    __syncthreads();

    if (t < 64) {
        const int row = row0 + t;
        const size_t pa = (size_t)row * 2;
        float av1 = pv1[pa + 0], av2 = pv2[pa + 0]; int ai1 = pi1[pa + 0];
        float bv1 = pv1[pa + 1], bv2 = pv2[pa + 1]; int bi1 = pi1[pa + 1];
        float v1; int i1; float v2;
        if (bv1 < av1) { v1 = bv1; i1 = bi1; v2 = fminf(av1, bv2); }
        else           { v1 = av1; i1 = ai1; v2 = fminf(bv1, av2); }  // tie: half0
        rowidx[t] = i1;
        bool flag = (v2 - v1 < MARGIN_MERGE) ||
                    (av2 - av1 < MARGIN_HALF) || (bv2 - bv1 < MARGIN_HALF);
        if (flag) { int p = atomicAdd(&nflag, 1); flr[p] = t; }   // LDS atomic; p < 64
    }
    __syncthreads();

    const size_t IOFF = (size_t)N * DIM;
    const size_t ROFF = IOFF + (size_t)N;
#pragma unroll
    for (int it = 0; it < 16; ++it) {
        const int rl  = it * 4 + w;
        const int row = row0 + rl;
        const int idx = rowidx[rl];
        if (l == 0) out[IOFF + row] = (float)idx;
        f32x4 e  = *reinterpret_cast<const f32x4*>(embed + (size_t)idx * DIM + l * 4);
        f32x4 xv = *reinterpret_cast<const f32x4*>(x + (size_t)row * DIM + l * 4);
        nt_store4(out + (size_t)row * DIM + l * 4, e);
        nt_store4(out + ROFF + (size_t)row * DIM + l * 4, e - xv);
    }

    // barrier: all output writes done before refine overwrites flagged rows
    __syncthreads();
    const int nf = nflag;   // stable since the pre-output barrier
    for (int f = 0; f < nf; ++f) {
        const int row = row0 + flr[f];
        float4 xv = *reinterpret_cast<const float4*>(x + (size_t)row * DIM + l * 4);
        const double x0 = xv.x, x1 = xv.y, x2 = xv.z, x3 = xv.w;

        double v1 = DBL_MAX, v2 = DBL_MAX; int i1 = 0x7fffffff, i2 = 0x7fffffff;
#pragma unroll 4
        for (int i = 0; i < 256; ++i) {          // ascending j within wave
            const int j = w * 256 + i;
            float4 ev = *reinterpret_cast<const float4*>(embed + (size_t)j * DIM + l * 4);
            double xe = (double)ev.x * x0 + (double)ev.y * x1
                      + (double)ev.z * x2 + (double)ev.w * x3;
#pragma unroll
            for (int m = 1; m < 64; m <<= 1) xe += __shfl_xor(xe, m, 64);
            double d = esqd[j] - 2.0 * xe;       // shift-invariant exact score
            if (d < v1) { v2 = v1; i2 = i1; v1 = d; i1 = j; }
            else if (d < v2) { v2 = d; i2 = j; }
        }
        if (l == 0) { sv1[w] = v1; si1[w] = i1; sv2[w] = v2; si2[w] = i2; }
        __syncthreads();
        if (t == 0) {
            double a1 = sv1[0], a2 = sv2[0]; int k1 = si1[0], k2 = si2[0];
#pragma unroll
            for (int ww = 1; ww < 4; ++ww) {
                double b1 = sv1[ww], b2 = sv2[ww]; int j1 = si1[ww], j2 = si2[ww];
                double w1, w2; int m1, m2;
                bool bfirst = (b1 < a1) || (b1 == a1 && j1 < k1);
                if (bfirst) {
                    w1 = b1; m1 = j1;
                    if (a1 < b2 || (a1 == b2 && k1 < j2)) { w2 = a1; m2 = k1; }
                    else                                   { w2 = b2; m2 = j2; }
                } else {
                    w1 = a1; m1 = k1;
                    if (b1 < a2 || (b1 == a2 && j1 < k2)) { w2 = b1; m2 = j1; }
                    else                                   { w2 = a2; m2 = k2; }
                }
                a1 = w1; k1 = m1; a2 = w2; k2 = m2;
            }
            int idx = k1;
            const double gap = a2 - a1;
#if PREFER_LOWER
            if (gap < EPS_TIE && k2 < k1) idx = k2;
#else
            if (gap < EPS_TIE && k2 > k1) idx = k2;
#endif
            sidx = idx;
        }
        __syncthreads();
        const int idx = sidx;
        if (t == 0) out[IOFF + row] = (float)idx;
        if (t < 64) {
            int d0 = t * 4;
            float4 e  = *reinterpret_cast<const float4*>(embed + (size_t)idx * DIM + d0);
            float4 xr = *reinterpret_cast<const float4*>(x + (size_t)row * DIM + d0);
            *reinterpret_cast<float4*>(out + (size_t)row * DIM + d0) = e;
            float4 rr = make_float4(e.x - xr.x, e.y - xr.y, e.z - xr.z, e.w - xr.w);
            *reinterpret_cast<float4*>(out + ROFF + (size_t)row * DIM + d0) = rr;
        }
        __syncthreads();   // protect sv/sidx before next flagged row
    }
}

// ================= fallback: R6-verified VALU path (used if ws too small) ====
#define BM 64
#define BN 64
#define DK 64
__global__ __launch_bounds__(256, 4)
void vq_argmin_kernel(const float* __restrict__ x, const float* __restrict__ embed,
                      const float* __restrict__ esq, float* __restrict__ out,
                      int N, int K) {
    __shared__ float xs[DK][BM];
    __shared__ float es[DK][BN];
    __shared__ double rv1[256], rv2[256];
    __shared__ int    ri1[256], ri2[256];
    __shared__ float  xrow[DIM];
    __shared__ int    flr[BM];
    __shared__ int    nflag;

    const int t = threadIdx.x;
    const int tx = t & 15, ty = t >> 4;
    const int row0 = blockIdx.x * BM;
    if (t == 0) nflag = 0;

    float minv[4], min2v[4]; int mini[4];
#pragma unroll
    for (int r = 0; r < 4; ++r) { minv[r] = INFINITY; min2v[r] = INFINITY; mini[r] = 0; }

    for (int jc = 0; jc < K / BN; ++jc) {
        float acc[4][4];
#pragma unroll
        for (int r = 0; r < 4; ++r)
#pragma unroll
            for (int c = 0; c < 4; ++c) acc[r][c] = 0.0f;
        for (int dc = 0; dc < DIM / DK; ++dc) {
            __syncthreads();
#pragma unroll
            for (int it = 0; it < 4; ++it) {
                int idx = t + 256 * it, r = idx & 63, kg = idx >> 6;
                float4 v = *reinterpret_cast<const float4*>(
                    x + (size_t)(row0 + r) * DIM + dc * DK + kg * 4);
                xs[kg*4+0][r] = v.x; xs[kg*4+1][r] = v.y; xs[kg*4+2][r] = v.z; xs[kg*4+3][r] = v.w;
            }
#pragma unroll
            for (int it = 0; it < 4; ++it) {
                int idx = t + 256 * it, c = idx & 63, kg = idx >> 6;
                float4 v = *reinterpret_cast<const float4*>(
                    embed + (size_t)(jc * BN + c) * DIM + dc * DK + kg * 4);
                es[kg*4+0][c] = v.x; es[kg*4+1][c] = v.y; es[kg*4+2][c] = v.z; es[kg*4+3][c] = v.w;
            }
            __syncthreads();
#pragma unroll
            for (int k = 0; k < DK; ++k) {
                float4 a = *reinterpret_cast<const float4*>(&xs[k][ty * 4]);
                float4 b = *reinterpret_cast<const float4*>(&es[k][tx * 4]);
                float arr[4] = {a.x, a.y, a.z, a.w}, bc[4] = {b.x, b.y, b.z, b.w};
#pragma unroll
                for (int r = 0; r < 4; ++r)
#pragma unroll
                    for (int c = 0; c < 4; ++c) acc[r][c] = fmaf(arr[r], bc[c], acc[r][c]);
            }
        }
        float4 eq = *reinterpret_cast<const float4*>(esq + jc * BN + tx * 4);
        float eqa[4] = {eq.x, eq.y, eq.z, eq.w};
#pragma unroll
        for (int c = 0; c < 4; ++c) {
            int j = jc * BN + tx * 4 + c;
#pragma unroll
            for (int r = 0; r < 4; ++r) {
                float s = fmaf(-2.0f, acc[r][c], eqa[c]);
                if (s < minv[r]) { min2v[r] = minv[r]; minv[r] = s; mini[r] = j; }
                else if (s < min2v[r]) { min2v[r] = s; }
            }
        }
    }
#pragma unroll
    for (int r = 0; r < 4; ++r) {
        float v1 = minv[r]; int i1 = mini[r]; float v2 = min2v[r];
#pragma unroll
        for (int m = 1; m < 16; m <<= 1) {
            float ov1 = __shfl_xor(v1, m, 64); int oi1 = __shfl_xor(i1, m, 64);
            float ov2 = __shfl_xor(v2, m, 64);
            float nv2 = fminf(fmaxf(v1, ov1), fminf(v2, ov2));
            if (ov1 < v1 || (ov1 == v1 && oi1 < i1)) { v1 = ov1; i1 = oi1; }
            v2 = nv2;
        }
        minv[r] = v1; mini[r] = i1; min2v[r] = v2;
    }
    const size_t IOFF = (size_t)N * DIM, ROFF = IOFF + (size_t)N;
#pragma unroll
    for (int r = 0; r < 4; ++r) {
        int row = row0 + ty * 4 + r, idx = mini[r];
        if (tx == 0) {
            out[IOFF + row] = (float)idx;
            if (min2v[r] - minv[r] < MARGIN_FALLBACK) { int p = atomicAdd(&nflag, 1); flr[p] = ty * 4 + r; }
        }
#pragma unroll
        for (int g = 0; g < 4; ++g) {
            int d0 = tx * 16 + g * 4;
            float4 e  = *reinterpret_cast<const float4*>(embed + (size_t)idx * DIM + d0);
            float4 xv = *reinterpret_cast<const float4*>(x + (size_t)row * DIM + d0);
            *reinterpret_cast<float4*>(out + (size_t)row * DIM + d0) = e;
            float4 rr = make_float4(e.x - xv.x, e.y - xv.y, e.z - xv.z, e.w - xv.w);
            *reinterpret_cast<float4*>(out + ROFF + (size_t)row * DIM + d0) = rr;
        }
    }
    __syncthreads();
    const int nf = nflag;
    for (int f = 0; f < nf; ++f) {
        const int row = row0 + flr[f];
        if (t < 64) {
            float4 v = *reinterpret_cast<const float4*>(x + (size_t)row * DIM + t * 4);
            xrow[t*4+0] = v.x; xrow[t*4+1] = v.y; xrow[t*4+2] = v.z; xrow[t*4+3] = v.w;
        }
        __syncthreads();
        double v1 = DBL_MAX, v2 = DBL_MAX; int i1 = 0x7fffffff, i2 = 0x7fffffff;
#pragma unroll
        for (int jj = 0; jj < 4; ++jj) {
            const int j = t * 4 + jj;
            const float* e = embed + (size_t)j * DIM;
            double xe = 0.0, ee = 0.0;
            for (int kg = 0; kg < DIM / 4; ++kg) {
                float4 ev = *reinterpret_cast<const float4*>(e + kg * 4);
                double e0 = ev.x, e1 = ev.y, e2 = ev.z, e3 = ev.w;
                xe += e0*(double)xrow[kg*4+0] + e1*(double)xrow[kg*4+1]
                    + e2*(double)xrow[kg*4+2] + e3*(double)xrow[kg*4+3];
                ee += e0*e0 + e1*e1 + e2*e2 + e3*e3;
            }
            double d = ee - 2.0 * xe;
            if (d < v1 || (d == v1 && j < i1)) { v2 = v1; i2 = i1; v1 = d; i1 = j; }
            else if (d < v2 || (d == v2 && j < i2)) { v2 = d; i2 = j; }
        }
        rv1[t] = v1; ri1[t] = i1; rv2[t] = v2; ri2[t] = i2;
        __syncthreads();
        for (int s = 128; s > 0; s >>= 1) {
            if (t < s) {
                double a1 = rv1[t], a2 = rv2[t]; int k1 = ri1[t], k2 = ri2[t];
                double b1 = rv1[t+s], b2 = rv2[t+s]; int j1 = ri1[t+s], j2 = ri2[t+s];
                double w1, w2; int m1, m2;
                bool bfirst = (b1 < a1) || (b1 == a1 && j1 < k1);
                if (bfirst) { w1 = b1; m1 = j1;
                    if (a1 < b2 || (a1 == b2 && k1 < j2)) { w2 = a1; m2 = k1; } else { w2 = b2; m2 = j2; }
                } else { w1 = a1; m1 = k1;
                    if (b1 < a2 || (b1 == a2 && j1 < k2)) { w2 = b1; m2 = j1; } else { w2 = a2; m2 = k2; }
                }
                rv1[t] = w1; ri1[t] = m1; rv2[t] = w2; ri2[t] = m2;
            }
            __syncthreads();
        }
        int idx = ri1[0];
        const double gap = rv2[0] - rv1[0];
#if PREFER_LOWER
        if (gap < EPS_TIE && ri2[0] < ri1[0]) idx = ri2[0];
#else
        if (gap < EPS_TIE && ri2[0] > ri1[0]) idx = ri2[0];
#endif
        if (t == 0) out[IOFF + row] = (float)idx;
        if (t < 64) {
            int d0 = t * 4;
            float4 e  = *reinterpret_cast<const float4*>(embed + (size_t)idx * DIM + d0);
            float4 xv = *reinterpret_cast<const float4*>(x + (size_t)row * DIM + d0);
            *reinterpret_cast<float4*>(out + (size_t)row * DIM + d0) = e;
            float4 rr = make_float4(e.x - xv.x, e.y - xv.y, e.z - xv.z, e.w - xv.w);
            *reinterpret_cast<float4*>(out + ROFF + (size_t)row * DIM + d0) = rr;
        }
        __syncthreads();
    }
}

extern "C" void kernel_launch(void* const* d_in, const int* in_sizes, int n_in,
                              void* d_out, int out_size, void* d_ws, size_t ws_size,
                              hipStream_t stream) {
    const float* x     = (const float*)d_in[0];
    const float* embed = (const float*)d_in[1];
    float* out = (float*)d_out;
    const int N = in_sizes[0] / DIM;   // 65536
    const int K = in_sizes[1] / DIM;   // 1024

    // ws layout (2.01 MB, all buffers write-before-read within one call):
    char* wsb = (char*)d_ws;
    float*          esq  = (float*)(wsb + 0);                 //   4 KB
    double*         esqd = (double*)(wsb + 4096);             //   8 KB -> 12288
    unsigned short* ehi  = (unsigned short*)(wsb + 12288);    // 512 KB -> 536576
    float*          pv1  = (float*)(wsb + 536576);            // 512 KB -> 1060864
    float*          pv2  = (float*)(wsb + 1060864);           // 512 KB -> 1585152
    int*            pi1  = (int*)(wsb + 1585152);             // 512 KB -> 2109440
    const size_t need = 2109440;

    if (ws_size >= need) {
        esq_kernel<<<K, 64, 0, stream>>>(embed, esq, esqd);
        efrag_kernel<<<(K / 16) * 8, 64, 0, stream>>>(embed, ehi);
        vq_fast_kernel<<<(N / 512) * 2, 512, 0, stream>>>(x, ehi, esq, pv1, pv2, pi1, N);
        vq_merge_refine_kernel<<<N / 64, 256, 0, stream>>>(x, embed, pv1, pv2, pi1,
                                                           esqd, out, N);
    } else {
        esq_kernel<<<K, 64, 0, stream>>>(embed, esq, esqd);
        vq_argmin_kernel<<<N / BM, 256, 0, stream>>>(x, embed, esq, out, N, K);
    }
}